// Round 15
// baseline (3760.496 us; speedup 1.0000x reference)
//
#include <hip/hip_runtime.h>
#include <cstdint>
#include <cstddef>

// ViT-B/16 + token pruning. Round 15: LN folded into qkv/fc1 GEMMs with
// stats computed OFF the critical path. stats_k (1 wave/row) produces
// mean/rstd; LNF GEMM inner loop is the clean R12 ring-3 loop; epilogue:
// out = rstd*(acc - mean*s[col]) + c[col]. Same algebra as R14 (passed),
// same GEMM speed as R12.

#define NTOK 197
#define NB 64
#define NHEAD 12
#define SL 99

typedef __attribute__((ext_vector_type(8))) _Float16 half8;
typedef __attribute__((ext_vector_type(4))) float f32x4;
typedef __attribute__((ext_vector_type(2))) float f32x2;
typedef __attribute__((ext_vector_type(4))) unsigned short us4;

#define DEV static __device__ __forceinline__

DEV unsigned short f2h(float f) {
    union { _Float16 h; unsigned short u; } v;
    v.h = (_Float16)f;
    return v.u;
}
DEV float h2f(unsigned short u) {
    union { _Float16 h; unsigned short u; } v;
    v.u = u;
    return (float)v.h;
}

DEV void gload16(const void* g, void* l) {
    __builtin_amdgcn_global_load_lds((const __attribute__((address_space(1))) unsigned int*)g,
                                     (__attribute__((address_space(3))) unsigned int*)l, 16, 0, 0);
}

// GELU with A&S 7.1.26 erf (|eps| <= 1.5e-7)
DEV float gelu_f(float v) {
    float x = v * 0.70710678118654752f;
    float ax = fabsf(x);
    float t = __builtin_amdgcn_rcpf(fmaf(0.3275911f, ax, 1.0f));
    float poly = fmaf(fmaf(fmaf(fmaf(1.061405429f, t, -1.453152027f), t,
                               1.421413741f), t, -0.284496736f), t, 0.254829592f) * t;
    float erf_ax = 1.0f - poly * __expf(-x * x);
    float er = (x < 0.f) ? -erf_ax : erf_ax;
    return 0.5f * v * (1.0f + er);
}

// ---------------------------------------------------------------- simple fp32->fp16 converter
__global__ __launch_bounds__(256) void cvt_simple_k(const float* __restrict__ src,
                                                    unsigned short* __restrict__ dh, int n4)
{
    int t = blockIdx.x * 256 + threadIdx.x;
    if (t >= n4) return;
    size_t e = (size_t)t * 4;
    float4 v = *(const float4*)(src + e);
    us4 hi; hi.x = f2h(v.x); hi.y = f2h(v.y); hi.z = f2h(v.z); hi.w = f2h(v.w);
    *(us4*)(dh + e) = hi;
}

// ---------------------------------------------------------------- ratio_k: bLN/g per (layer, which, k)
__global__ __launch_bounds__(256) void ratio_k(const float* __restrict__ ln1_g, const float* __restrict__ ln1_b,
                                               const float* __restrict__ ln2_g, const float* __restrict__ ln2_b,
                                               float* __restrict__ ratio)
{
    int idx = blockIdx.x * 256 + threadIdx.x;    // < 12*2*768
    if (idx >= 18432) return;
    int l = idx / 1536, wh = (idx / 768) & 1, k = idx % 768;
    float g = wh ? ln2_g[l * 768 + k] : ln1_g[l * 768 + k];
    float b = wh ? ln2_b[l * 768 + k] : ln1_b[l * 768 + k];
    ratio[idx] = (g != 0.f) ? b / g : 0.f;
}

// ---------------------------------------------------------------- weight conversion (4 layers, gamma-scaled)
__global__ __launch_bounds__(256) void cvt_layer4_k(const float* __restrict__ qw,
                                                    const float* __restrict__ pw,
                                                    const float* __restrict__ f1,
                                                    const float* __restrict__ f2,
                                                    const float* __restrict__ ln1_g,
                                                    const float* __restrict__ ln2_g,
                                                    int i0,
                                                    unsigned short* __restrict__ dst)
{
    int l = blockIdx.x / 6912;
    int b2 = blockIdx.x % 6912;
    int li = i0 + l;
    size_t t = (size_t)b2 * 256 + threadIdx.x;
    size_t e = t * 4;
    const float* src; size_t loc;
    const float* gsc = nullptr;
    if (e < 1769472)      { src = qw + (size_t)li * 1769472; loc = e; gsc = ln1_g + (size_t)li * 768; }
    else if (e < 2359296) { src = pw + (size_t)li * 589824;  loc = e - 1769472; }
    else if (e < 4718592) { src = f1 + (size_t)li * 2359296; loc = e - 2359296; gsc = ln2_g + (size_t)li * 768; }
    else                  { src = f2 + (size_t)li * 2359296; loc = e - 4718592; }
    float4 v = *(const float4*)(src + loc);
    if (gsc) {
        int k = (int)(loc % 768);
        float4 gv = *(const float4*)(gsc + k);
        v.x *= gv.x; v.y *= gv.y; v.z *= gv.z; v.w *= gv.w;
    }
    us4 hi; hi.x = f2h(v.x); hi.y = f2h(v.y); hi.z = f2h(v.z); hi.w = f2h(v.w);
    *(us4*)(dst + (size_t)l * 7077888 + e) = hi;
}

// ---------------------------------------------------------------- sc_k: s[n]=sum Wg16, c[n]=sum ratio*Wg16 + bias
__global__ __launch_bounds__(256) void sc_k(const unsigned short* __restrict__ wb4,
                                            const float* __restrict__ ratio,
                                            const float* __restrict__ qkv_b,
                                            const float* __restrict__ fc1_b,
                                            int i0,
                                            float* __restrict__ sArr, float* __restrict__ cArr)
{
    int l = blockIdx.x / 1344;
    int row = (blockIdx.x % 1344) * 4 + (threadIdx.x >> 6);
    int lane = threadIdx.x & 63;
    int li = i0 + l;
    bool isq = row < 2304;
    const unsigned short* wrow = wb4 + (size_t)l * 7077888 +
        (isq ? (size_t)row * 768 : 2359296 + (size_t)(row - 2304) * 768);
    const float* rat = ratio + ((size_t)li * 2 + (isq ? 0 : 1)) * 768;
    float bias = isq ? qkv_b[(size_t)li * 2304 + row] : fc1_b[(size_t)li * 3072 + row - 2304];
    int e0 = lane * 12;
    us4 a = *(const us4*)(wrow + e0);
    us4 b = *(const us4*)(wrow + e0 + 4);
    us4 c = *(const us4*)(wrow + e0 + 8);
    float4 r0 = *(const float4*)(rat + e0), r1 = *(const float4*)(rat + e0 + 4), r2 = *(const float4*)(rat + e0 + 8);
    float v[12] = {h2f(a.x),h2f(a.y),h2f(a.z),h2f(a.w), h2f(b.x),h2f(b.y),h2f(b.z),h2f(b.w),
                   h2f(c.x),h2f(c.y),h2f(c.z),h2f(c.w)};
    float rr[12] = {r0.x,r0.y,r0.z,r0.w, r1.x,r1.y,r1.z,r1.w, r2.x,r2.y,r2.z,r2.w};
    float s = 0.f, cc = 0.f;
#pragma unroll
    for (int e = 0; e < 12; e++) { s += v[e]; cc = fmaf(rr[e], v[e], cc); }
#pragma unroll
    for (int o = 32; o; o >>= 1) { s += __shfl_xor(s, o); cc += __shfl_xor(cc, o); }
    if (lane == 0) {
        sArr[(size_t)l * 5376 + row] = s;
        cArr[(size_t)l * 5376 + row] = cc + bias;
    }
}

// ---------------------------------------------------------------- stats_k: per-row mean & rstd (fp16 in)
__global__ __launch_bounds__(64) void stats_k(const unsigned short* __restrict__ x,
                                              f32x2* __restrict__ st)
{
    const unsigned short* xr = x + (size_t)blockIdx.x * 768;
    const int t = threadIdx.x;
    const int e0 = t * 12;
    us4 a = *(const us4*)(xr + e0);
    us4 b = *(const us4*)(xr + e0 + 4);
    us4 c = *(const us4*)(xr + e0 + 8);
    float v[12] = {h2f(a.x),h2f(a.y),h2f(a.z),h2f(a.w), h2f(b.x),h2f(b.y),h2f(b.z),h2f(b.w),
                   h2f(c.x),h2f(c.y),h2f(c.z),h2f(c.w)};
    float s = 0.f, q = 0.f;
#pragma unroll
    for (int e = 0; e < 12; e++) { s += v[e]; q = fmaf(v[e], v[e], q); }
#pragma unroll
    for (int o = 32; o; o >>= 1) { s += __shfl_xor(s, o); q += __shfl_xor(q, o); }
    if (t == 0) {
        float mean = s * (1.f / 768.f);
        float var = q * (1.f / 768.f) - mean * mean;
        f32x2 r; r.x = mean; r.y = rsqrtf(var + 1e-6f);
        st[blockIdx.x] = r;
    }
}

// ---------------------------------------------------------------- patch extract
__global__ __launch_bounds__(256) void patch_extract2_k(const float* __restrict__ img,
                                                        unsigned short* __restrict__ ph)
{
    int pi = blockIdx.x, b = blockIdx.y;
    int gy = pi / 14, gx = pi % 14;
    size_t obase = ((size_t)b * 196 + pi) * 768;
    for (int f = threadIdx.x; f < 768; f += 256) {
        int c = f >> 8, py = (f >> 4) & 15, px = f & 15;
        float v = img[(((size_t)b * 3 + c) * 224 + gy * 16 + py) * 224 + gx * 16 + px];
        ph[obase + f] = f2h(v);
    }
}

__global__ __launch_bounds__(256) void assemble_k(const unsigned short* __restrict__ emb,
                                                  const float* __restrict__ cls,
                                                  const float* __restrict__ pos,
                                                  unsigned short* __restrict__ x)
{
    int s = blockIdx.x, b = blockIdx.y;
    size_t xo = ((size_t)b * NTOK + s) * 768;
    for (int d = threadIdx.x; d < 768; d += 256) {
        float v = (s == 0) ? cls[d] : h2f(emb[((size_t)b * 196 + (s - 1)) * 768 + d]);
        x[xo + d] = f2h(v + pos[(size_t)s * 768 + d]);
    }
}

// ---------------------------------------------------------------- 1-wave vectorized layernorm (final norm only)
__global__ __launch_bounds__(64) void lnw_k(const unsigned short* __restrict__ in,
                                            unsigned short* __restrict__ outh,
                                            const float* __restrict__ g,
                                            const float* __restrict__ bt, size_t ldin)
{
    const unsigned short* xr = in + (size_t)blockIdx.x * ldin;
    size_t ob = (size_t)blockIdx.x * 768;
    const int t = threadIdx.x;
    const int e0 = t * 12;
    us4 a = *(const us4*)(xr + e0);
    us4 b = *(const us4*)(xr + e0 + 4);
    us4 c = *(const us4*)(xr + e0 + 8);
    float v[12];
    v[0] = h2f(a.x); v[1] = h2f(a.y); v[2]  = h2f(a.z); v[3]  = h2f(a.w);
    v[4] = h2f(b.x); v[5] = h2f(b.y); v[6]  = h2f(b.z); v[7]  = h2f(b.w);
    v[8] = h2f(c.x); v[9] = h2f(c.y); v[10] = h2f(c.z); v[11] = h2f(c.w);
    float s = 0.f;
#pragma unroll
    for (int e = 0; e < 12; e++) s += v[e];
#pragma unroll
    for (int o = 32; o; o >>= 1) s += __shfl_xor(s, o);
    float mean = s * (1.f / 768.f);
    float ss = 0.f;
#pragma unroll
    for (int e = 0; e < 12; e++) { float d = v[e] - mean; ss += d * d; }
#pragma unroll
    for (int o = 32; o; o >>= 1) ss += __shfl_xor(ss, o);
    float inv = rsqrtf(ss * (1.f / 768.f) + 1e-6f);
    float4 g0 = *(const float4*)(g + e0),  g1 = *(const float4*)(g + e0 + 4),  g2 = *(const float4*)(g + e0 + 8);
    float4 b0 = *(const float4*)(bt + e0), b1 = *(const float4*)(bt + e0 + 4), b2 = *(const float4*)(bt + e0 + 8);
    float gg[12] = {g0.x,g0.y,g0.z,g0.w, g1.x,g1.y,g1.z,g1.w, g2.x,g2.y,g2.z,g2.w};
    float bb[12] = {b0.x,b0.y,b0.z,b0.w, b1.x,b1.y,b1.z,b1.w, b2.x,b2.y,b2.z,b2.w};
    unsigned short o16[12];
#pragma unroll
    for (int e = 0; e < 12; e++) o16[e] = f2h((v[e] - mean) * inv * gg[e] + bb[e]);
    us4 oa = {o16[0], o16[1], o16[2],  o16[3]};
    us4 obv = {o16[4], o16[5], o16[6],  o16[7]};
    us4 oc = {o16[8], o16[9], o16[10], o16[11]};
    *(us4*)(outh + ob + e0)     = oa;
    *(us4*)(outh + ob + e0 + 4) = obv;
    *(us4*)(outh + ob + e0 + 8) = oc;
}

// ---------------------------------------------------------------- 128x128 fp16 GEMM, ring-3, epilogue LN-fold
// EPI: 0 none, 1 GELU, 2 +res(fp16). OS: 0 fp32 out, 1 fp16 out.
// MAP: 0 linear; 3 chunked rows-fastest; 4 chunked cols-fastest.
// LNF: A is RAW x; per-row mean/rstd from stats[]; out = rstd*(acc - mean*sArr[col]) + bias[col].
template<int EPI, int OS, int MAP, int LNF>
__global__ __launch_bounds__(256) void mgemm_k(const unsigned short* __restrict__ Ah,
                                               const unsigned short* __restrict__ Wh,
                                               const float* __restrict__ bias,
                                               const float* __restrict__ sArr,
                                               const f32x2* __restrict__ stats,
                                               const unsigned short* __restrict__ res,
                                               unsigned short* __restrict__ Chi,
                                               float* __restrict__ Cf,
                                               int M, int N, int K, int nR, int nC, int nRloc)
{
    __shared__ unsigned short lds[3 * 8192];

    int rt, ct;
    {
        int bid = blockIdx.x;
        if (MAP == 0) { rt = bid % nR; ct = bid / nR; }
        else {
            int xcd = bid & 7, u = bid >> 3, rl, c;
            if (MAP == 3) { rl = u % nRloc; c = u / nRloc; }
            else          { c = u % nC;     rl = u / nC;   }
            rt = xcd * nRloc + rl; ct = c;
            if (rt >= nR) return;
        }
    }
    const int row0 = rt << 7, col0 = ct << 7;
    const int tid = threadIdx.x;
    const int w = tid >> 6, lane = tid & 63;
    const int wr = w >> 1, wc = w & 1;
    const int srow = lane >> 2;
    const int schunk = ((lane & 3) ^ ((srow >> 1) & 3)) << 3;
    const int fr = lane & 15, fq = lane >> 4;
    const int rchunk = (fq ^ ((fr >> 1) & 3)) << 3;

    f32x4 acc[4][4];
#pragma unroll
    for (int m = 0; m < 4; m++)
#pragma unroll
        for (int n = 0; n < 4; n++) acc[m][n] = (f32x4)0.f;

    const int nk = K >> 5;

    auto stage = [&](int t, int slot) {
        const int k0 = t << 5;
        unsigned short* Ad = lds + slot * 8192;
        unsigned short* Bd = Ad + 4096;
#pragma unroll
        for (int i = 0; i < 2; i++) {
            int r = i * 64 + w * 16 + srow;
            int ga = row0 + r; if (ga > M - 1) ga = M - 1;
            int gb = col0 + r; if (gb > N - 1) gb = N - 1;
            gload16(Ah + (size_t)ga * K + k0 + schunk, Ad + i * 2048 + w * 512);
            gload16(Wh + (size_t)gb * K + k0 + schunk, Bd + i * 2048 + w * 512);
        }
    };

    stage(0, 0);
    stage(1, 1);
    int slot = 0, slot2 = 2;
    for (int t = 0; t < nk; ++t) {
        if (t + 1 < nk) asm volatile("s_waitcnt vmcnt(4)" ::: "memory");
        else            asm volatile("s_waitcnt vmcnt(0)" ::: "memory");
        __builtin_amdgcn_s_barrier();
        if (t + 2 < nk) stage(t + 2, slot2);
        const unsigned short* Ab = lds + slot * 8192;
        const unsigned short* Bb = Ab + 4096;
        half8 a[4], bb[4];
#pragma unroll
        for (int m = 0; m < 4; m++)
            a[m] = *(const half8*)(Ab + (wr * 64 + m * 16 + fr) * 32 + rchunk);
#pragma unroll
        for (int n = 0; n < 4; n++)
            bb[n] = *(const half8*)(Bb + (wc * 64 + n * 16 + fr) * 32 + rchunk);
#pragma unroll
        for (int m = 0; m < 4; m++)
#pragma unroll
            for (int n = 0; n < 4; n++)
                acc[m][n] = __builtin_amdgcn_mfma_f32_16x16x32_f16(a[m], bb[n], acc[m][n], 0, 0, 0);
        slot = (slot == 2) ? 0 : slot + 1;
        slot2 = (slot2 == 2) ? 0 : slot2 + 1;
    }

#pragma unroll
    for (int m = 0; m < 4; m++) {
        float mean_r[4], rstd_r[4];
        if (LNF) {
#pragma unroll
            for (int r = 0; r < 4; r++) {
                int row = row0 + wr * 64 + m * 16 + fq * 4 + r;
                f32x2 st = stats[row < M ? row : M - 1];
                mean_r[r] = st.x;
                rstd_r[r] = st.y;
            }
        }
#pragma unroll
        for (int n = 0; n < 4; n++) {
            int col = col0 + wc * 64 + n * 16 + fr;
            float sv = 0.f;
            if (LNF && col < N) sv = sArr[col];
#pragma unroll
            for (int r = 0; r < 4; r++) {
                int row = row0 + wr * 64 + m * 16 + fq * 4 + r;
                if (row < M && col < N) {
                    float v;
                    if (LNF) v = rstd_r[r] * (acc[m][n][r] - mean_r[r] * sv) + bias[col];
                    else     v = acc[m][n][r] + bias[col];
                    size_t o = (size_t)row * N + col;
                    if (EPI == 2) v += h2f(res[o]);
                    if (EPI == 1) v = gelu_f(v);
                    if (OS == 0) Cf[o] = v;
                    else Chi[o] = f2h(v);
                }
            }
        }
    }
}

// ---------------------------------------------------------------- fused MFMA attention (fp16, setprio)
template<int S, int KT, int PVKT, int PSTR>
__global__ __launch_bounds__(256) void attn2_k(const unsigned short* __restrict__ qh,
                                               unsigned short* __restrict__ oh,
                                               const int* __restrict__ cntp)
{
    constexpr int PVK = PVKT * 32;
    constexpr int QT = (S + 15) / 16;
    extern __shared__ unsigned short sh[];
    unsigned short* VT = sh;
    unsigned short* PL = sh + 64 * PSTR;

    const int h = blockIdx.x, b = blockIdx.y;
    const int tid = threadIdx.x, w = tid >> 6, lane = tid & 63;
    const int nk = cntp ? cntp[b] : S;
    const size_t qbase = (size_t)b * S * 2304 + (size_t)h * 64;
    const int fr = lane & 15, fq = lane >> 4;

    for (int j0 = 0; j0 < S; j0 += 32) {
        int j = j0 + (tid >> 3);
        int d8 = (tid & 7) * 8;
        if (j < S) {
            size_t src = qbase + (size_t)j * 2304 + 1536 + d8;
            us4 v0 = *(const us4*)(qh + src);
            us4 v1 = *(const us4*)(qh + src + 4);
            VT[(d8 + 0) * PSTR + j] = v0.x; VT[(d8 + 1) * PSTR + j] = v0.y;
            VT[(d8 + 2) * PSTR + j] = v0.z; VT[(d8 + 3) * PSTR + j] = v0.w;
            VT[(d8 + 4) * PSTR + j] = v1.x; VT[(d8 + 5) * PSTR + j] = v1.y;
            VT[(d8 + 6) * PSTR + j] = v1.z; VT[(d8 + 7) * PSTR + j] = v1.w;
        }
    }
    for (int idx = tid; idx < 64 * (PVK - S); idx += 256) {
        int d = idx / (PVK - S), j = S + idx % (PVK - S);
        VT[d * PSTR + j] = 0;
    }
    {
        unsigned short* Pw = PL + w * 16 * PSTR;
        for (int idx = lane; idx < 16 * (PVK - 16 * KT); idx += 64) {
            int rr = idx / (PVK - 16 * KT), cc = 16 * KT + idx % (PVK - 16 * KT);
            Pw[rr * PSTR + cc] = 0;
        }
    }
    __syncthreads();

    for (int qt = w; qt < QT; qt += 4) {
        int qr = qt * 16 + fr; int qrc = qr < S ? qr : S - 1;
        const size_t qrow = qbase + (size_t)qrc * 2304;
        half8 qf0[2];
#pragma unroll
        for (int ks = 0; ks < 2; ks++)
            qf0[ks] = *(const half8*)(qh + qrow + ks * 32 + fq * 8);
        f32x4 sc[KT];
        __builtin_amdgcn_s_setprio(1);
#pragma unroll
        for (int kt = 0; kt < KT; kt++) {
            int ky = kt * 16 + fr; int kyc = ky < S ? ky : S - 1;
            const size_t krow = qbase + (size_t)kyc * 2304 + 768;
            f32x4 acc = (f32x4)0.f;
#pragma unroll
            for (int ks = 0; ks < 2; ks++) {
                half8 kh = *(const half8*)(qh + krow + ks * 32 + fq * 8);
                acc = __builtin_amdgcn_mfma_f32_16x16x32_f16(qf0[ks], kh, acc, 0, 0, 0);
            }
            sc[kt] = acc;
        }
        __builtin_amdgcn_s_setprio(0);
        float mx[4] = {-3e38f, -3e38f, -3e38f, -3e38f};
#pragma unroll
        for (int kt = 0; kt < KT; kt++) {
            bool valid = (kt * 16 + fr) < nk;
#pragma unroll
            for (int r = 0; r < 4; r++) {
                float s = sc[kt][r] * 0.125f;
                sc[kt][r] = s;
                if (valid) mx[r] = fmaxf(mx[r], s);
            }
        }
#pragma unroll
        for (int off = 1; off < 16; off <<= 1)
#pragma unroll
            for (int r = 0; r < 4; r++) mx[r] = fmaxf(mx[r], __shfl_xor(mx[r], off));
        float sum[4] = {0.f, 0.f, 0.f, 0.f};
#pragma unroll
        for (int kt = 0; kt < KT; kt++) {
            bool valid = (kt * 16 + fr) < nk;
#pragma unroll
            for (int r = 0; r < 4; r++) {
                float p = valid ? __expf(sc[kt][r] - mx[r]) : 0.f;
                sc[kt][r] = p;
                sum[r] += p;
            }
        }
#pragma unroll
        for (int off = 1; off < 16; off <<= 1)
#pragma unroll
            for (int r = 0; r < 4; r++) sum[r] += __shfl_xor(sum[r], off);
        float inv[4];
#pragma unroll
        for (int r = 0; r < 4; r++) inv[r] = 1.f / sum[r];
        unsigned short* Pw = PL + w * 16 * PSTR;
#pragma unroll
        for (int kt = 0; kt < KT; kt++) {
#pragma unroll
            for (int r = 0; r < 4; r++)
                Pw[(fq * 4 + r) * PSTR + kt * 16 + fr] = f2h(sc[kt][r] * inv[r]);
        }
        f32x4 o[4];
#pragma unroll
        for (int n = 0; n < 4; n++) o[n] = (f32x4)0.f;
        __builtin_amdgcn_s_setprio(1);
#pragma unroll
        for (int ks = 0; ks < PVKT; ks++) {
            half8 pa = *(const half8*)(Pw + fr * PSTR + ks * 32 + fq * 8);
#pragma unroll
            for (int n = 0; n < 4; n++) {
                half8 vb = *(const half8*)(VT + (n * 16 + fr) * PSTR + ks * 32 + fq * 8);
                o[n] = __builtin_amdgcn_mfma_f32_16x16x32_f16(pa, vb, o[n], 0, 0, 0);
            }
        }
        __builtin_amdgcn_s_setprio(0);
#pragma unroll
        for (int n = 0; n < 4; n++) {
#pragma unroll
            for (int r = 0; r < 4; r++) {
                int row = qt * 16 + fq * 4 + r;
                if (row < S) {
                    size_t oidx = ((size_t)b * S + row) * 768 + (size_t)h * 64 + n * 16 + fr;
                    oh[oidx] = f2h(o[n][r]);
                }
            }
        }
    }
}

// ---------------------------------------------------------------- prune machinery (1-wave, vectorized)
__global__ __launch_bounds__(64) void normsq_k(const unsigned short* __restrict__ x,
                                               float* __restrict__ norms)
{
    const unsigned short* xr = x + (size_t)blockIdx.x * 768;
    const int t = threadIdx.x;
    const int e0 = t * 12;
    us4 a = *(const us4*)(xr + e0);
    us4 b = *(const us4*)(xr + e0 + 4);
    us4 c = *(const us4*)(xr + e0 + 8);
    float ss = 0.f;
    float v;
    v = h2f(a.x); ss += v * v; v = h2f(a.y); ss += v * v;
    v = h2f(a.z); ss += v * v; v = h2f(a.w); ss += v * v;
    v = h2f(b.x); ss += v * v; v = h2f(b.y); ss += v * v;
    v = h2f(b.z); ss += v * v; v = h2f(b.w); ss += v * v;
    v = h2f(c.x); ss += v * v; v = h2f(c.y); ss += v * v;
    v = h2f(c.z); ss += v * v; v = h2f(c.w); ss += v * v;
#pragma unroll
    for (int o = 32; o; o >>= 1) ss += __shfl_xor(ss, o);
    if (t == 0) norms[blockIdx.x] = ss;
}

__global__ __launch_bounds__(256) void topk_k(const float* __restrict__ norms,
                                              int* __restrict__ idxmap, int* __restrict__ cnt)
{
    int b = blockIdx.x, t = threadIdx.x;
    __shared__ float n[NTOK];
    __shared__ unsigned char kp[NTOK];
    if (t < NTOK) n[t] = norms[b * NTOK + t];
    __syncthreads();
    if (t < NTOK) {
        float me = n[t];
        int rank = 0;
        for (int j = 0; j < NTOK; j++) rank += (n[j] > me) || (n[j] == me && j < t);
        kp[t] = (rank < 98) || (t == 0);
    }
    __syncthreads();
    if (t == 0) {
        int c = 0;
        for (int s = 0; s < NTOK; s++) if (kp[s]) idxmap[b * SL + c++] = s;
        cnt[b] = c;
        for (int j = c; j < SL; j++) idxmap[b * SL + j] = 0;
    }
}

__global__ __launch_bounds__(64) void gather_k(const unsigned short* __restrict__ x,
                                               const int* __restrict__ idxmap,
                                               const int* __restrict__ cnt,
                                               unsigned short* __restrict__ xl)
{
    int j = blockIdx.x, b = blockIdx.y;
    size_t dst = ((size_t)b * SL + j) * 768;
    const int t = threadIdx.x;
    const int e0 = t * 12;
    if (j < cnt[b]) {
        int s = idxmap[b * SL + j];
        size_t src = ((size_t)b * NTOK + s) * 768;
        *(us4*)(xl + dst + e0)     = *(const us4*)(x + src + e0);
        *(us4*)(xl + dst + e0 + 4) = *(const us4*)(x + src + e0 + 4);
        *(us4*)(xl + dst + e0 + 8) = *(const us4*)(x + src + e0 + 8);
    } else {
        us4 z = {0, 0, 0, 0};
        *(us4*)(xl + dst + e0)     = z;
        *(us4*)(xl + dst + e0 + 4) = z;
        *(us4*)(xl + dst + e0 + 8) = z;
    }
}

// ---------------------------------------------------------------- launch
extern "C" void kernel_launch(void* const* d_in, const int* in_sizes, int n_in,
                              void* d_out, int out_size, void* d_ws, size_t ws_size,
                              hipStream_t stream)
{
    const float* images  = (const float*)d_in[0];
    const float* patch_w = (const float*)d_in[1];
    const float* patch_b = (const float*)d_in[2];
    const float* cls_tok = (const float*)d_in[3];
    const float* pos_emb = (const float*)d_in[4];
    const float* ln1_g   = (const float*)d_in[5];
    const float* ln1_b   = (const float*)d_in[6];
    const float* qkv_w   = (const float*)d_in[7];
    const float* qkv_b   = (const float*)d_in[8];
    const float* proj_w  = (const float*)d_in[9];
    const float* proj_b  = (const float*)d_in[10];
    const float* ln2_g   = (const float*)d_in[11];
    const float* ln2_b   = (const float*)d_in[12];
    const float* fc1_w   = (const float*)d_in[13];
    const float* fc1_b   = (const float*)d_in[14];
    const float* fc2_w   = (const float*)d_in[15];
    const float* fc2_b   = (const float*)d_in[16];
    const float* norm_g  = (const float*)d_in[17];
    const float* norm_b  = (const float*)d_in[18];
    const float* head_w  = (const float*)d_in[19];
    const float* head_b  = (const float*)d_in[20];
    float* outp = (float*)d_out;

    char* W = (char*)d_ws;
    unsigned short* x16  = (unsigned short*)W;                   // 19,365,888
    unsigned short* hbh  = (unsigned short*)(W + 19365888);      // attn-out
    char* R = W + 38731776;                                      // 77,463,552 shared
    unsigned short* ph   = (unsigned short*)R;
    unsigned short* emb  = (unsigned short*)(R + 19365888);
    unsigned short* qkh  = (unsigned short*)R;
    unsigned short* ffh  = (unsigned short*)R;
    unsigned short* xl16 = (unsigned short*)(W + 116195328);
    unsigned short* wb4  = (unsigned short*)(W + 125927424);     // 4 layers x 14,155,776
    unsigned short* pwh  = (unsigned short*)(W + 182550528);
    unsigned short* hwb  = (unsigned short*)(W + 183730176);
    float* norms         = (float*)(W + 185303040);
    unsigned short* clsb = (unsigned short*)(W + 185353472);
    int* idxmap          = (int*)(W + 185451776);
    int* cnt             = (int*)(W + 185477120);
    float* sArr          = (float*)(W + 185477632);              // 4*5376
    float* cArr          = (float*)(W + 185563648);              // 4*5376
    float* ratio         = (float*)(W + 185649664);              // 12*2*768
    f32x2* stats         = (f32x2*)(W + 185729024);              // 12608 f32x2

    const int LDS_EARLY = (64 * 232 + 4 * 16 * 232) * 2;   // 59,392
    const int LDS_LATE  = (64 * 136 + 4 * 16 * 136) * 2;   // 34,816
    (void)hipFuncSetAttribute(reinterpret_cast<const void*>(&attn2_k<197, 13, 7, 232>),
                              hipFuncAttributeMaxDynamicSharedMemorySize, LDS_EARLY);
    (void)hipFuncSetAttribute(reinterpret_cast<const void*>(&attn2_k<99, 7, 4, 136>),
                              hipFuncAttributeMaxDynamicSharedMemorySize, LDS_LATE);

    const int nR1 = 99, nRl1 = 13;     // M = 12608
    const int nRp = 98, nRlp = 13;     // patch M = 12544
    const int nR2 = 50, nRl2 = 7;      // M = 6336

    ratio_k<<<72, 256, 0, stream>>>(ln1_g, ln1_b, ln2_g, ln2_b, ratio);

    // ---- patch embed ----
    cvt_simple_k<<<576, 256, 0, stream>>>(patch_w, pwh, 147456);
    patch_extract2_k<<<dim3(196, NB), 256, 0, stream>>>(images, ph);
    mgemm_k<0, 1, 3, 0><<<8 * nRlp * 6, 256, 0, stream>>>(ph, pwh, patch_b, nullptr, nullptr,
        nullptr, emb, nullptr, 12544, 768, 768, nRp, 6, nRlp);
    assemble_k<<<dim3(NTOK, NB), 256, 0, stream>>>(emb, cls_tok, pos_emb, x16);

    const int M1 = NB * NTOK;   // 12608
    for (int i = 0; i < 4; i++) {
        if (i == 0) {
            cvt_layer4_k<<<4 * 6912, 256, 0, stream>>>(qkv_w, proj_w, fc1_w, fc2_w, ln1_g, ln2_g, 0, wb4);
            sc_k<<<4 * 1344, 256, 0, stream>>>(wb4, ratio, qkv_b, fc1_b, 0, sArr, cArr);
        }
        unsigned short* wbh = wb4 + (size_t)(i & 3) * 7077888;
        float* sL = sArr + (size_t)(i & 3) * 5376;
        float* cL = cArr + (size_t)(i & 3) * 5376;
        stats_k<<<M1, 64, 0, stream>>>(x16, stats);
        mgemm_k<0, 1, 3, 1><<<8 * nRl1 * 18, 256, 0, stream>>>(x16, wbh,
            cL, sL, stats, nullptr, qkh, nullptr, M1, 2304, 768, nR1, 18, nRl1);
        attn2_k<197, 13, 7, 232><<<dim3(NHEAD, NB), 256, LDS_EARLY, stream>>>(qkh, hbh, nullptr);
        mgemm_k<2, 1, 3, 0><<<8 * nRl1 * 6, 256, 0, stream>>>(hbh, wbh + 1769472,
            proj_b + (size_t)i * 768, nullptr, nullptr, x16, x16, nullptr, M1, 768, 768, nR1, 6, nRl1);
        stats_k<<<M1, 64, 0, stream>>>(x16, stats);
        mgemm_k<1, 1, 3, 1><<<8 * nRl1 * 24, 256, 0, stream>>>(x16, wbh + 2359296,
            cL + 2304, sL + 2304, stats, nullptr, ffh, nullptr, M1, 3072, 768, nR1, 24, nRl1);
        mgemm_k<2, 1, 4, 0><<<8 * nRl1 * 6, 256, 0, stream>>>(ffh, wbh + 4718592,
            fc2_b + (size_t)i * 768, nullptr, nullptr, x16, x16, nullptr, M1, 768, 3072, nR1, 6, nRl1);
    }

    // ---- prune + compact ----
    normsq_k<<<M1, 64, 0, stream>>>(x16, norms);
    topk_k<<<NB, 256, 0, stream>>>(norms, idxmap, cnt);
    gather_k<<<dim3(SL, NB), 64, 0, stream>>>(x16, idxmap, cnt, xl16);

    const int M2 = NB * SL;     // 6336
    for (int i = 4; i < 12; i++) {
        if (i == 4) {
            cvt_layer4_k<<<4 * 6912, 256, 0, stream>>>(qkv_w, proj_w, fc1_w, fc2_w, ln1_g, ln2_g, 4, wb4);
            sc_k<<<4 * 1344, 256, 0, stream>>>(wb4, ratio, qkv_b, fc1_b, 4, sArr, cArr);
        }
        if (i == 8) {
            cvt_layer4_k<<<4 * 6912, 256, 0, stream>>>(qkv_w, proj_w, fc1_w, fc2_w, ln1_g, ln2_g, 8, wb4);
            sc_k<<<4 * 1344, 256, 0, stream>>>(wb4, ratio, qkv_b, fc1_b, 8, sArr, cArr);
        }
        unsigned short* wbh = wb4 + (size_t)(i & 3) * 7077888;
        float* sL = sArr + (size_t)(i & 3) * 5376;
        float* cL = cArr + (size_t)(i & 3) * 5376;
        stats_k<<<M2, 64, 0, stream>>>(xl16, stats);
        mgemm_k<0, 1, 3, 1><<<8 * nRl2 * 18, 256, 0, stream>>>(xl16, wbh,
            cL, sL, stats, nullptr, qkh, nullptr, M2, 2304, 768, nR2, 18, nRl2);
        attn2_k<99, 7, 4, 136><<<dim3(NHEAD, NB), 256, LDS_LATE, stream>>>(qkh, hbh, cnt);
        mgemm_k<2, 1, 3, 0><<<8 * nRl2 * 6, 256, 0, stream>>>(hbh, wbh + 1769472,
            proj_b + (size_t)i * 768, nullptr, nullptr, xl16, xl16, nullptr, M2, 768, 768, nR2, 6, nRl2);
        stats_k<<<M2, 64, 0, stream>>>(xl16, stats);
        mgemm_k<1, 1, 3, 1><<<8 * nRl2 * 24, 256, 0, stream>>>(xl16, wbh + 2359296,
            cL + 2304, sL + 2304, stats, nullptr, ffh, nullptr, M2, 3072, 768, nR2, 24, nRl2);
        mgemm_k<2, 1, 4, 0><<<8 * nRl2 * 6, 256, 0, stream>>>(ffh, wbh + 4718592,
            fc2_b + (size_t)i * 768, nullptr, nullptr, xl16, xl16, nullptr, M2, 768, 3072, nR2, 6, nRl2);
    }

    // ---- final LN(CLS) + head ----
    lnw_k<<<NB, 64, 0, stream>>>(xl16, clsb, norm_g, norm_b, (size_t)SL * 768);
    cvt_simple_k<<<750, 256, 0, stream>>>(head_w, hwb, 192000);
    mgemm_k<0, 0, 0, 0><<<8, 256, 0, stream>>>(clsb, hwb,
        head_b, nullptr, nullptr, nullptr, nullptr, outp, 64, 1000, 768, 1, 8, 1);
}

// Round 16
// 3730.268 us; speedup vs baseline: 1.0081x; 1.0081x over previous
//
#include <hip/hip_runtime.h>
#include <cstdint>
#include <cstddef>

// ViT-B/16 + token pruning. Round 16 = exact revert to R12 (best measured:
// 3733 us, absmax 0.0262). fp16 everywhere; ring-3 counted-vmcnt 128^2 MFMA
// GEMM with chunked-XCD mapping; fused MFMA attention with setprio; 1-wave
// vectorized LN/normsq/gather; poly-GELU.
// Ledger: R13-R15 LN-fold arc = neutral; five GEMM-schedule variants all at
// the ~460 TF fp16 2-phase structural ceiling -> stop-loss to best state.

#define NTOK 197
#define NB 64
#define NHEAD 12
#define SL 99

typedef __attribute__((ext_vector_type(8))) _Float16 half8;
typedef __attribute__((ext_vector_type(4))) float f32x4;
typedef __attribute__((ext_vector_type(4))) unsigned short us4;

#define DEV static __device__ __forceinline__

DEV unsigned short f2h(float f) {
    union { _Float16 h; unsigned short u; } v;
    v.h = (_Float16)f;
    return v.u;
}
DEV float h2f(unsigned short u) {
    union { _Float16 h; unsigned short u; } v;
    v.u = u;
    return (float)v.h;
}

DEV void gload16(const void* g, void* l) {
    __builtin_amdgcn_global_load_lds((const __attribute__((address_space(1))) unsigned int*)g,
                                     (__attribute__((address_space(3))) unsigned int*)l, 16, 0, 0);
}

// GELU with Abramowitz-Stegun 7.1.26 erf (|eps| <= 1.5e-7)
DEV float gelu_f(float v) {
    float x = v * 0.70710678118654752f;
    float ax = fabsf(x);
    float t = __builtin_amdgcn_rcpf(fmaf(0.3275911f, ax, 1.0f));
    float poly = fmaf(fmaf(fmaf(fmaf(1.061405429f, t, -1.453152027f), t,
                               1.421413741f), t, -0.284496736f), t, 0.254829592f) * t;
    float erf_ax = 1.0f - poly * __expf(-x * x);
    float er = (x < 0.f) ? -erf_ax : erf_ax;
    return 0.5f * v * (1.0f + er);
}

// ---------------------------------------------------------------- weight conversion (4 layers / launch)
__global__ __launch_bounds__(256) void cvt_layer4_k(const float* __restrict__ qw,
                                                    const float* __restrict__ pw,
                                                    const float* __restrict__ f1,
                                                    const float* __restrict__ f2,
                                                    int i0,
                                                    unsigned short* __restrict__ dst)
{
    int l = blockIdx.x / 6912;
    int b2 = blockIdx.x % 6912;
    int li = i0 + l;
    size_t t = (size_t)b2 * 256 + threadIdx.x;
    size_t e = t * 4;
    const float* src; size_t loc;
    if (e < 1769472)      { src = qw + (size_t)li * 1769472; loc = e; }
    else if (e < 2359296) { src = pw + (size_t)li * 589824;  loc = e - 1769472; }
    else if (e < 4718592) { src = f1 + (size_t)li * 2359296; loc = e - 2359296; }
    else                  { src = f2 + (size_t)li * 2359296; loc = e - 4718592; }
    float4 v = *(const float4*)(src + loc);
    us4 hi; hi.x = f2h(v.x); hi.y = f2h(v.y); hi.z = f2h(v.z); hi.w = f2h(v.w);
    *(us4*)(dst + (size_t)l * 7077888 + e) = hi;
}

__global__ __launch_bounds__(256) void cvt_simple_k(const float* __restrict__ src,
                                                    unsigned short* __restrict__ dh, int n4)
{
    int t = blockIdx.x * 256 + threadIdx.x;
    if (t >= n4) return;
    size_t e = (size_t)t * 4;
    float4 v = *(const float4*)(src + e);
    us4 hi; hi.x = f2h(v.x); hi.y = f2h(v.y); hi.z = f2h(v.z); hi.w = f2h(v.w);
    *(us4*)(dh + e) = hi;
}

// ---------------------------------------------------------------- patch extract
__global__ __launch_bounds__(256) void patch_extract2_k(const float* __restrict__ img,
                                                        unsigned short* __restrict__ ph)
{
    int pi = blockIdx.x, b = blockIdx.y;
    int gy = pi / 14, gx = pi % 14;
    size_t obase = ((size_t)b * 196 + pi) * 768;
    for (int f = threadIdx.x; f < 768; f += 256) {
        int c = f >> 8, py = (f >> 4) & 15, px = f & 15;
        float v = img[(((size_t)b * 3 + c) * 224 + gy * 16 + py) * 224 + gx * 16 + px];
        ph[obase + f] = f2h(v);
    }
}

__global__ __launch_bounds__(256) void assemble_k(const unsigned short* __restrict__ emb,
                                                  const float* __restrict__ cls,
                                                  const float* __restrict__ pos,
                                                  unsigned short* __restrict__ x)
{
    int s = blockIdx.x, b = blockIdx.y;
    size_t xo = ((size_t)b * NTOK + s) * 768;
    for (int d = threadIdx.x; d < 768; d += 256) {
        float v = (s == 0) ? cls[d] : h2f(emb[((size_t)b * 196 + (s - 1)) * 768 + d]);
        x[xo + d] = f2h(v + pos[(size_t)s * 768 + d]);
    }
}

// ---------------------------------------------------------------- 1-wave vectorized layernorm (fp16->fp16)
__global__ __launch_bounds__(64) void lnw_k(const unsigned short* __restrict__ in,
                                            unsigned short* __restrict__ outh,
                                            const float* __restrict__ g,
                                            const float* __restrict__ bt, size_t ldin)
{
    const unsigned short* xr = in + (size_t)blockIdx.x * ldin;
    size_t ob = (size_t)blockIdx.x * 768;
    const int t = threadIdx.x;            // 0..63
    const int e0 = t * 12;

    us4 a = *(const us4*)(xr + e0);
    us4 b = *(const us4*)(xr + e0 + 4);
    us4 c = *(const us4*)(xr + e0 + 8);
    float v[12];
    v[0] = h2f(a.x); v[1] = h2f(a.y); v[2]  = h2f(a.z); v[3]  = h2f(a.w);
    v[4] = h2f(b.x); v[5] = h2f(b.y); v[6]  = h2f(b.z); v[7]  = h2f(b.w);
    v[8] = h2f(c.x); v[9] = h2f(c.y); v[10] = h2f(c.z); v[11] = h2f(c.w);

    float s = 0.f;
#pragma unroll
    for (int e = 0; e < 12; e++) s += v[e];
#pragma unroll
    for (int o = 32; o; o >>= 1) s += __shfl_xor(s, o);
    float mean = s * (1.f / 768.f);
    float ss = 0.f;
#pragma unroll
    for (int e = 0; e < 12; e++) { float d = v[e] - mean; ss += d * d; }
#pragma unroll
    for (int o = 32; o; o >>= 1) ss += __shfl_xor(ss, o);
    float inv = rsqrtf(ss * (1.f / 768.f) + 1e-6f);

    float4 g0 = *(const float4*)(g + e0),  g1 = *(const float4*)(g + e0 + 4),  g2 = *(const float4*)(g + e0 + 8);
    float4 b0 = *(const float4*)(bt + e0), b1 = *(const float4*)(bt + e0 + 4), b2 = *(const float4*)(bt + e0 + 8);
    float gg[12] = {g0.x,g0.y,g0.z,g0.w, g1.x,g1.y,g1.z,g1.w, g2.x,g2.y,g2.z,g2.w};
    float bb[12] = {b0.x,b0.y,b0.z,b0.w, b1.x,b1.y,b1.z,b1.w, b2.x,b2.y,b2.z,b2.w};
    unsigned short o16[12];
#pragma unroll
    for (int e = 0; e < 12; e++) o16[e] = f2h((v[e] - mean) * inv * gg[e] + bb[e]);
    us4 oa = {o16[0], o16[1], o16[2],  o16[3]};
    us4 obv = {o16[4], o16[5], o16[6],  o16[7]};
    us4 oc = {o16[8], o16[9], o16[10], o16[11]};
    *(us4*)(outh + ob + e0)     = oa;
    *(us4*)(outh + ob + e0 + 4) = obv;
    *(us4*)(outh + ob + e0 + 8) = oc;
}

// ---------------------------------------------------------------- 128x128 fp16 GEMM, ring-3 pipeline
// EPI: 0 none, 1 GELU, 2 +res(fp16). OS: 0 fp32 out, 1 fp16 out.
// MAP: 0 linear; 3 chunked-XCD rows-fastest; 4 chunked-XCD cols-fastest.
template<int EPI, int OS, int MAP>
__global__ __launch_bounds__(256) void mgemm_k(const unsigned short* __restrict__ Ah,
                                               const unsigned short* __restrict__ Wh,
                                               const float* __restrict__ bias,
                                               const unsigned short* __restrict__ res,
                                               unsigned short* __restrict__ Chi,
                                               float* __restrict__ Cf,
                                               int M, int N, int K, int nR, int nC, int nRloc)
{
    __shared__ unsigned short lds[3 * 8192];

    int rt, ct;
    {
        int bid = blockIdx.x;
        if (MAP == 0) { rt = bid % nR; ct = bid / nR; }
        else {
            int xcd = bid & 7, u = bid >> 3, rl, c;
            if (MAP == 3) { rl = u % nRloc; c = u / nRloc; }
            else          { c = u % nC;     rl = u / nC;   }
            rt = xcd * nRloc + rl; ct = c;
            if (rt >= nR) return;
        }
    }
    const int row0 = rt << 7, col0 = ct << 7;
    const int tid = threadIdx.x;
    const int w = tid >> 6, lane = tid & 63;
    const int wr = w >> 1, wc = w & 1;
    const int srow = lane >> 2;
    const int schunk = ((lane & 3) ^ ((srow >> 1) & 3)) << 3;
    const int fr = lane & 15, fq = lane >> 4;
    const int rchunk = (fq ^ ((fr >> 1) & 3)) << 3;

    f32x4 acc[4][4];
#pragma unroll
    for (int m = 0; m < 4; m++)
#pragma unroll
        for (int n = 0; n < 4; n++) acc[m][n] = (f32x4)0.f;

    const int nk = K >> 5;

    auto stage = [&](int t, int slot) {
        const int k0 = t << 5;
        unsigned short* Ad = lds + slot * 8192;
        unsigned short* Bd = Ad + 4096;
#pragma unroll
        for (int i = 0; i < 2; i++) {
            int r = i * 64 + w * 16 + srow;
            int ga = row0 + r; if (ga > M - 1) ga = M - 1;
            int gb = col0 + r; if (gb > N - 1) gb = N - 1;
            gload16(Ah + (size_t)ga * K + k0 + schunk, Ad + i * 2048 + w * 512);
            gload16(Wh + (size_t)gb * K + k0 + schunk, Bd + i * 2048 + w * 512);
        }
    };

    stage(0, 0);
    stage(1, 1);
    int slot = 0, slot2 = 2;
    for (int t = 0; t < nk; ++t) {
        if (t + 1 < nk) asm volatile("s_waitcnt vmcnt(4)" ::: "memory");
        else            asm volatile("s_waitcnt vmcnt(0)" ::: "memory");
        __builtin_amdgcn_s_barrier();
        if (t + 2 < nk) stage(t + 2, slot2);
        const unsigned short* Ab = lds + slot * 8192;
        const unsigned short* Bb = Ab + 4096;
        half8 a[4], bb[4];
#pragma unroll
        for (int m = 0; m < 4; m++)
            a[m] = *(const half8*)(Ab + (wr * 64 + m * 16 + fr) * 32 + rchunk);
#pragma unroll
        for (int n = 0; n < 4; n++)
            bb[n] = *(const half8*)(Bb + (wc * 64 + n * 16 + fr) * 32 + rchunk);
#pragma unroll
        for (int m = 0; m < 4; m++)
#pragma unroll
            for (int n = 0; n < 4; n++)
                acc[m][n] = __builtin_amdgcn_mfma_f32_16x16x32_f16(a[m], bb[n], acc[m][n], 0, 0, 0);
        slot = (slot == 2) ? 0 : slot + 1;
        slot2 = (slot2 == 2) ? 0 : slot2 + 1;
    }

#pragma unroll
    for (int m = 0; m < 4; m++) {
#pragma unroll
        for (int n = 0; n < 4; n++) {
            int col = col0 + wc * 64 + n * 16 + fr;
#pragma unroll
            for (int r = 0; r < 4; r++) {
                int row = row0 + wr * 64 + m * 16 + fq * 4 + r;
                if (row < M && col < N) {
                    float v = acc[m][n][r] + bias[col];
                    size_t o = (size_t)row * N + col;
                    if (EPI == 2) v += h2f(res[o]);
                    if (EPI == 1) v = gelu_f(v);
                    if (OS == 0) Cf[o] = v;
                    else Chi[o] = f2h(v);
                }
            }
        }
    }
}

// ---------------------------------------------------------------- fused MFMA attention (fp16, +setprio)
template<int S, int KT, int PVKT, int PSTR>
__global__ __launch_bounds__(256) void attn2_k(const unsigned short* __restrict__ qh,
                                               unsigned short* __restrict__ oh,
                                               const int* __restrict__ cntp)
{
    constexpr int PVK = PVKT * 32;
    constexpr int QT = (S + 15) / 16;
    extern __shared__ unsigned short sh[];
    unsigned short* VT = sh;
    unsigned short* PL = sh + 64 * PSTR;

    const int h = blockIdx.x, b = blockIdx.y;
    const int tid = threadIdx.x, w = tid >> 6, lane = tid & 63;
    const int nk = cntp ? cntp[b] : S;
    const size_t qbase = (size_t)b * S * 2304 + (size_t)h * 64;
    const int fr = lane & 15, fq = lane >> 4;

    for (int j0 = 0; j0 < S; j0 += 32) {
        int j = j0 + (tid >> 3);
        int d8 = (tid & 7) * 8;
        if (j < S) {
            size_t src = qbase + (size_t)j * 2304 + 1536 + d8;
            us4 v0 = *(const us4*)(qh + src);
            us4 v1 = *(const us4*)(qh + src + 4);
            VT[(d8 + 0) * PSTR + j] = v0.x; VT[(d8 + 1) * PSTR + j] = v0.y;
            VT[(d8 + 2) * PSTR + j] = v0.z; VT[(d8 + 3) * PSTR + j] = v0.w;
            VT[(d8 + 4) * PSTR + j] = v1.x; VT[(d8 + 5) * PSTR + j] = v1.y;
            VT[(d8 + 6) * PSTR + j] = v1.z; VT[(d8 + 7) * PSTR + j] = v1.w;
        }
    }
    for (int idx = tid; idx < 64 * (PVK - S); idx += 256) {
        int d = idx / (PVK - S), j = S + idx % (PVK - S);
        VT[d * PSTR + j] = 0;
    }
    {
        unsigned short* Pw = PL + w * 16 * PSTR;
        for (int idx = lane; idx < 16 * (PVK - 16 * KT); idx += 64) {
            int rr = idx / (PVK - 16 * KT), cc = 16 * KT + idx % (PVK - 16 * KT);
            Pw[rr * PSTR + cc] = 0;
        }
    }
    __syncthreads();

    for (int qt = w; qt < QT; qt += 4) {
        int qr = qt * 16 + fr; int qrc = qr < S ? qr : S - 1;
        const size_t qrow = qbase + (size_t)qrc * 2304;
        half8 qf0[2];
#pragma unroll
        for (int ks = 0; ks < 2; ks++)
            qf0[ks] = *(const half8*)(qh + qrow + ks * 32 + fq * 8);
        f32x4 sc[KT];
        __builtin_amdgcn_s_setprio(1);
#pragma unroll
        for (int kt = 0; kt < KT; kt++) {
            int ky = kt * 16 + fr; int kyc = ky < S ? ky : S - 1;
            const size_t krow = qbase + (size_t)kyc * 2304 + 768;
            f32x4 acc = (f32x4)0.f;
#pragma unroll
            for (int ks = 0; ks < 2; ks++) {
                half8 kh = *(const half8*)(qh + krow + ks * 32 + fq * 8);
                acc = __builtin_amdgcn_mfma_f32_16x16x32_f16(qf0[ks], kh, acc, 0, 0, 0);
            }
            sc[kt] = acc;
        }
        __builtin_amdgcn_s_setprio(0);
        float mx[4] = {-3e38f, -3e38f, -3e38f, -3e38f};
#pragma unroll
        for (int kt = 0; kt < KT; kt++) {
            bool valid = (kt * 16 + fr) < nk;
#pragma unroll
            for (int r = 0; r < 4; r++) {
                float s = sc[kt][r] * 0.125f;
                sc[kt][r] = s;
                if (valid) mx[r] = fmaxf(mx[r], s);
            }
        }
#pragma unroll
        for (int off = 1; off < 16; off <<= 1)
#pragma unroll
            for (int r = 0; r < 4; r++) mx[r] = fmaxf(mx[r], __shfl_xor(mx[r], off));
        float sum[4] = {0.f, 0.f, 0.f, 0.f};
#pragma unroll
        for (int kt = 0; kt < KT; kt++) {
            bool valid = (kt * 16 + fr) < nk;
#pragma unroll
            for (int r = 0; r < 4; r++) {
                float p = valid ? __expf(sc[kt][r] - mx[r]) : 0.f;
                sc[kt][r] = p;
                sum[r] += p;
            }
        }
#pragma unroll
        for (int off = 1; off < 16; off <<= 1)
#pragma unroll
            for (int r = 0; r < 4; r++) sum[r] += __shfl_xor(sum[r], off);
        float inv[4];
#pragma unroll
        for (int r = 0; r < 4; r++) inv[r] = 1.f / sum[r];
        unsigned short* Pw = PL + w * 16 * PSTR;
#pragma unroll
        for (int kt = 0; kt < KT; kt++) {
#pragma unroll
            for (int r = 0; r < 4; r++)
                Pw[(fq * 4 + r) * PSTR + kt * 16 + fr] = f2h(sc[kt][r] * inv[r]);
        }
        f32x4 o[4];
#pragma unroll
        for (int n = 0; n < 4; n++) o[n] = (f32x4)0.f;
        __builtin_amdgcn_s_setprio(1);
#pragma unroll
        for (int ks = 0; ks < PVKT; ks++) {
            half8 pa = *(const half8*)(Pw + fr * PSTR + ks * 32 + fq * 8);
#pragma unroll
            for (int n = 0; n < 4; n++) {
                half8 vb = *(const half8*)(VT + (n * 16 + fr) * PSTR + ks * 32 + fq * 8);
                o[n] = __builtin_amdgcn_mfma_f32_16x16x32_f16(pa, vb, o[n], 0, 0, 0);
            }
        }
        __builtin_amdgcn_s_setprio(0);
#pragma unroll
        for (int n = 0; n < 4; n++) {
#pragma unroll
            for (int r = 0; r < 4; r++) {
                int row = qt * 16 + fq * 4 + r;
                if (row < S) {
                    size_t oidx = ((size_t)b * S + row) * 768 + (size_t)h * 64 + n * 16 + fr;
                    oh[oidx] = f2h(o[n][r]);
                }
            }
        }
    }
}

// ---------------------------------------------------------------- prune machinery (1-wave, vectorized)
__global__ __launch_bounds__(64) void normsq_k(const unsigned short* __restrict__ x,
                                               float* __restrict__ norms)
{
    const unsigned short* xr = x + (size_t)blockIdx.x * 768;
    const int t = threadIdx.x;
    const int e0 = t * 12;
    us4 a = *(const us4*)(xr + e0);
    us4 b = *(const us4*)(xr + e0 + 4);
    us4 c = *(const us4*)(xr + e0 + 8);
    float ss = 0.f;
    float v;
    v = h2f(a.x); ss += v * v; v = h2f(a.y); ss += v * v;
    v = h2f(a.z); ss += v * v; v = h2f(a.w); ss += v * v;
    v = h2f(b.x); ss += v * v; v = h2f(b.y); ss += v * v;
    v = h2f(b.z); ss += v * v; v = h2f(b.w); ss += v * v;
    v = h2f(c.x); ss += v * v; v = h2f(c.y); ss += v * v;
    v = h2f(c.z); ss += v * v; v = h2f(c.w); ss += v * v;
#pragma unroll
    for (int o = 32; o; o >>= 1) ss += __shfl_xor(ss, o);
    if (t == 0) norms[blockIdx.x] = ss;
}

__global__ __launch_bounds__(256) void topk_k(const float* __restrict__ norms,
                                              int* __restrict__ idxmap, int* __restrict__ cnt)
{
    int b = blockIdx.x, t = threadIdx.x;
    __shared__ float n[NTOK];
    __shared__ unsigned char kp[NTOK];
    if (t < NTOK) n[t] = norms[b * NTOK + t];
    __syncthreads();
    if (t < NTOK) {
        float me = n[t];
        int rank = 0;
        for (int j = 0; j < NTOK; j++) rank += (n[j] > me) || (n[j] == me && j < t);
        kp[t] = (rank < 98) || (t == 0);
    }
    __syncthreads();
    if (t == 0) {
        int c = 0;
        for (int s = 0; s < NTOK; s++) if (kp[s]) idxmap[b * SL + c++] = s;
        cnt[b] = c;
        for (int j = c; j < SL; j++) idxmap[b * SL + j] = 0;
    }
}

__global__ __launch_bounds__(64) void gather_k(const unsigned short* __restrict__ x,
                                               const int* __restrict__ idxmap,
                                               const int* __restrict__ cnt,
                                               unsigned short* __restrict__ xl)
{
    int j = blockIdx.x, b = blockIdx.y;
    size_t dst = ((size_t)b * SL + j) * 768;
    const int t = threadIdx.x;
    const int e0 = t * 12;
    if (j < cnt[b]) {
        int s = idxmap[b * SL + j];
        size_t src = ((size_t)b * NTOK + s) * 768;
        *(us4*)(xl + dst + e0)     = *(const us4*)(x + src + e0);
        *(us4*)(xl + dst + e0 + 4) = *(const us4*)(x + src + e0 + 4);
        *(us4*)(xl + dst + e0 + 8) = *(const us4*)(x + src + e0 + 8);
    } else {
        us4 z = {0, 0, 0, 0};
        *(us4*)(xl + dst + e0)     = z;
        *(us4*)(xl + dst + e0 + 4) = z;
        *(us4*)(xl + dst + e0 + 8) = z;
    }
}

// ---------------------------------------------------------------- launch
extern "C" void kernel_launch(void* const* d_in, const int* in_sizes, int n_in,
                              void* d_out, int out_size, void* d_ws, size_t ws_size,
                              hipStream_t stream)
{
    const float* images  = (const float*)d_in[0];
    const float* patch_w = (const float*)d_in[1];
    const float* patch_b = (const float*)d_in[2];
    const float* cls_tok = (const float*)d_in[3];
    const float* pos_emb = (const float*)d_in[4];
    const float* ln1_g   = (const float*)d_in[5];
    const float* ln1_b   = (const float*)d_in[6];
    const float* qkv_w   = (const float*)d_in[7];
    const float* qkv_b   = (const float*)d_in[8];
    const float* proj_w  = (const float*)d_in[9];
    const float* proj_b  = (const float*)d_in[10];
    const float* ln2_g   = (const float*)d_in[11];
    const float* ln2_b   = (const float*)d_in[12];
    const float* fc1_w   = (const float*)d_in[13];
    const float* fc1_b   = (const float*)d_in[14];
    const float* fc2_w   = (const float*)d_in[15];
    const float* fc2_b   = (const float*)d_in[16];
    const float* norm_g  = (const float*)d_in[17];
    const float* norm_b  = (const float*)d_in[18];
    const float* head_w  = (const float*)d_in[19];
    const float* head_b  = (const float*)d_in[20];
    float* outp = (float*)d_out;

    char* W = (char*)d_ws;
    unsigned short* x16  = (unsigned short*)W;                   // 19,365,888
    unsigned short* hbh  = (unsigned short*)(W + 19365888);      // 19,365,888
    char* R = W + 38731776;                                      // 77,463,552 shared
    unsigned short* ph   = (unsigned short*)R;
    unsigned short* emb  = (unsigned short*)(R + 19365888);
    unsigned short* qkh  = (unsigned short*)R;
    unsigned short* ffh  = (unsigned short*)R;
    unsigned short* xl16 = (unsigned short*)(W + 116195328);
    unsigned short* wb4  = (unsigned short*)(W + 125927424);     // 4 layers x 14,155,776
    unsigned short* pwh  = (unsigned short*)(W + 182550528);
    unsigned short* hwb  = (unsigned short*)(W + 183730176);
    float* norms         = (float*)(W + 185303040);
    unsigned short* clsb = (unsigned short*)(W + 185353472);
    int* idxmap          = (int*)(W + 185451776);
    int* cnt             = (int*)(W + 185477120);

    const int LDS_EARLY = (64 * 232 + 4 * 16 * 232) * 2;   // 59,392
    const int LDS_LATE  = (64 * 136 + 4 * 16 * 136) * 2;   // 34,816
    (void)hipFuncSetAttribute(reinterpret_cast<const void*>(&attn2_k<197, 13, 7, 232>),
                              hipFuncAttributeMaxDynamicSharedMemorySize, LDS_EARLY);
    (void)hipFuncSetAttribute(reinterpret_cast<const void*>(&attn2_k<99, 7, 4, 136>),
                              hipFuncAttributeMaxDynamicSharedMemorySize, LDS_LATE);

    // chunked grids: grid = 8 * nRloc * nC, nRloc = ceil(nR/8); 128-row tiles
    const int nR1 = 99, nRl1 = 13;     // M = 12608
    const int nRp = 98, nRlp = 13;     // patch M = 12544
    const int nR2 = 50, nRl2 = 7;      // M = 6336

    // ---- patch embed ----
    cvt_simple_k<<<576, 256, 0, stream>>>(patch_w, pwh, 147456);
    patch_extract2_k<<<dim3(196, NB), 256, 0, stream>>>(images, ph);
    mgemm_k<0, 1, 3><<<8 * nRlp * 6, 256, 0, stream>>>(ph, pwh, patch_b, nullptr,
        emb, nullptr, 12544, 768, 768, nRp, 6, nRlp);
    assemble_k<<<dim3(NTOK, NB), 256, 0, stream>>>(emb, cls_tok, pos_emb, x16);

    const int M1 = NB * NTOK;   // 12608
    for (int i = 0; i < 4; i++) {
        if (i == 0)
            cvt_layer4_k<<<4 * 6912, 256, 0, stream>>>(qkv_w, proj_w, fc1_w, fc2_w, 0, wb4);
        unsigned short* wbh = wb4 + (size_t)(i & 3) * 7077888;
        lnw_k<<<M1, 64, 0, stream>>>(x16, hbh, ln1_g + (size_t)i * 768, ln1_b + (size_t)i * 768, 768);
        mgemm_k<0, 1, 3><<<8 * nRl1 * 18, 256, 0, stream>>>(hbh, wbh,
            qkv_b + (size_t)i * 2304, nullptr, qkh, nullptr, M1, 2304, 768, nR1, 18, nRl1);
        attn2_k<197, 13, 7, 232><<<dim3(NHEAD, NB), 256, LDS_EARLY, stream>>>(qkh, hbh, nullptr);
        mgemm_k<2, 1, 3><<<8 * nRl1 * 6, 256, 0, stream>>>(hbh, wbh + 1769472,
            proj_b + (size_t)i * 768, x16, x16, nullptr, M1, 768, 768, nR1, 6, nRl1);
        lnw_k<<<M1, 64, 0, stream>>>(x16, hbh, ln2_g + (size_t)i * 768, ln2_b + (size_t)i * 768, 768);
        mgemm_k<1, 1, 3><<<8 * nRl1 * 24, 256, 0, stream>>>(hbh, wbh + 2359296,
            fc1_b + (size_t)i * 3072, nullptr, ffh, nullptr, M1, 3072, 768, nR1, 24, nRl1);
        mgemm_k<2, 1, 4><<<8 * nRl1 * 6, 256, 0, stream>>>(ffh, wbh + 4718592,
            fc2_b + (size_t)i * 768, x16, x16, nullptr, M1, 768, 3072, nR1, 6, nRl1);
    }

    // ---- prune + compact ----
    normsq_k<<<M1, 64, 0, stream>>>(x16, norms);
    topk_k<<<NB, 256, 0, stream>>>(norms, idxmap, cnt);
    gather_k<<<dim3(SL, NB), 64, 0, stream>>>(x16, idxmap, cnt, xl16);

    const int M2 = NB * SL;     // 6336
    for (int i = 4; i < 12; i++) {
        if (i == 4)
            cvt_layer4_k<<<4 * 6912, 256, 0, stream>>>(qkv_w, proj_w, fc1_w, fc2_w, 4, wb4);
        if (i == 8)
            cvt_layer4_k<<<4 * 6912, 256, 0, stream>>>(qkv_w, proj_w, fc1_w, fc2_w, 8, wb4);
        unsigned short* wbh = wb4 + (size_t)(i & 3) * 7077888;
        lnw_k<<<M2, 64, 0, stream>>>(xl16, hbh, ln1_g + (size_t)i * 768, ln1_b + (size_t)i * 768, 768);
        mgemm_k<0, 1, 3><<<8 * nRl2 * 18, 256, 0, stream>>>(hbh, wbh,
            qkv_b + (size_t)i * 2304, nullptr, qkh, nullptr, M2, 2304, 768, nR2, 18, nRl2);
        attn2_k<99, 7, 4, 136><<<dim3(NHEAD, NB), 256, LDS_LATE, stream>>>(qkh, hbh, cnt);
        mgemm_k<2, 1, 3><<<8 * nRl2 * 6, 256, 0, stream>>>(hbh, wbh + 1769472,
            proj_b + (size_t)i * 768, xl16, xl16, nullptr, M2, 768, 768, nR2, 6, nRl2);
        lnw_k<<<M2, 64, 0, stream>>>(xl16, hbh, ln2_g + (size_t)i * 768, ln2_b + (size_t)i * 768, 768);
        mgemm_k<1, 1, 3><<<8 * nRl2 * 24, 256, 0, stream>>>(hbh, wbh + 2359296,
            fc1_b + (size_t)i * 3072, nullptr, ffh, nullptr, M2, 3072, 768, nR2, 24, nRl2);
        mgemm_k<2, 1, 4><<<8 * nRl2 * 6, 256, 0, stream>>>(ffh, wbh + 4718592,
            fc2_b + (size_t)i * 768, xl16, xl16, nullptr, M2, 768, 3072, nR2, 6, nRl2);
    }

    // ---- final LN(CLS) + head ----
    lnw_k<<<NB, 64, 0, stream>>>(xl16, clsb, norm_g, norm_b, (size_t)SL * 768);
    cvt_simple_k<<<750, 256, 0, stream>>>(head_w, hwb, 192000);
    mgemm_k<0, 0, 0><<<8, 256, 0, stream>>>(clsb, hwb,
        head_b, nullptr, nullptr, outp, 64, 1000, 768, 1, 8, 1);
}